// Round 1
// baseline (218.586 us; speedup 1.0000x reference)
//
#include <hip/hip_runtime.h>

// LIF forward scan: x[T, N] fp32 -> spikes[T, N] fp32, N = B*C*H*W.
// Per-column independent recurrence:
//   v = v + (x_t - v) / 2          (TAU = 2.0; *0.5f is exact, FMA-safe)
//   s = (v - 1.0 >= 0) ? 1 : 0     (V_THRESHOLD = 1.0)
//   v = (1 - s) * v                (hard reset)
// Memory-bound: 1 GiB traffic, floor ~165 us at 6.3 TB/s.

__global__ __launch_bounds__(256) void lif_fwd_kernel(
    const float4* __restrict__ x, float4* __restrict__ out,
    int n4, int T) {
  int n = blockIdx.x * blockDim.x + threadIdx.x;
  if (n >= n4) return;

  float vx = 0.0f, vy = 0.0f, vz = 0.0f, vw = 0.0f;

  for (int t = 0; t < T; ++t) {
    float4 xt = x[(size_t)t * n4 + n];

    // leaky integrate: v = v + (x - v) * 0.5  (matches reference rounding;
    // mul by 0.5 is exact so fma(d,0.5,v) == v + (d*0.5) bitwise)
    vx = vx + (xt.x - vx) * 0.5f;
    vy = vy + (xt.y - vy) * 0.5f;
    vz = vz + (xt.z - vz) * 0.5f;
    vw = vw + (xt.w - vw) * 0.5f;

    // fire: heaviside(v - 1.0), 1 for >= 0
    float4 s;
    s.x = (vx - 1.0f >= 0.0f) ? 1.0f : 0.0f;
    s.y = (vy - 1.0f >= 0.0f) ? 1.0f : 0.0f;
    s.z = (vz - 1.0f >= 0.0f) ? 1.0f : 0.0f;
    s.w = (vw - 1.0f >= 0.0f) ? 1.0f : 0.0f;

    // hard reset (zero v where spiked)
    vx = (1.0f - s.x) * vx;
    vy = (1.0f - s.y) * vy;
    vz = (1.0f - s.z) * vz;
    vw = (1.0f - s.w) * vw;

    out[(size_t)t * n4 + n] = s;
  }
}

extern "C" void kernel_launch(void* const* d_in, const int* in_sizes, int n_in,
                              void* d_out, int out_size, void* d_ws, size_t ws_size,
                              hipStream_t stream) {
  const float* x = (const float*)d_in[0];
  float* out = (float*)d_out;

  const int T = 32;
  const int total = in_sizes[0];        // T * N
  const int N = total / T;              // 4,194,304
  const int n4 = N / 4;                 // 1,048,576 float4 columns

  const int block = 256;
  const int grid = (n4 + block - 1) / block;  // 4096 blocks

  lif_fwd_kernel<<<grid, block, 0, stream>>>(
      (const float4*)x, (float4*)out, n4, T);
}

// Round 3
// 195.221 us; speedup vs baseline: 1.1197x; 1.1197x over previous
//
#include <hip/hip_runtime.h>

// LIF forward scan: x[T, N] fp32 -> spikes[T, N] fp32, N = B*C*H*W = 4,194,304.
// Per-column recurrence (exact reference arithmetic, absmax 0.0 in R1):
//   v = v + (x_t - v) * 0.5   (TAU=2; *0.5 exact -> FMA-contraction-safe)
//   s = (v - 1.0 >= 0) ? 1 : 0
//   v = (1 - s) * v
//
// R3 = R2 with native Clang vector type (ext_vector_type(4)) so
// __builtin_nontemporal_load/store accept the pointers (HIP_vector_type
// float4 is a struct -> rejected, R2 compile failure).
//
// R2/R3 changes vs R1 (218.6 us, 4.9 TB/s eff):
//  - 2 float4 columns per thread, block-strided (i, i+256): each wave
//    load/store is 64 lanes x 16 B contiguous.
//  - register double-buffer: issue t+1 loads before computing/storing t
//    -> ~4 wave-loads in flight per wave (was 1).
//  - grid = 2048 blocks = 8192 waves = one full residency batch
//    (32 waves/CU), no second batch, no tail.
//  - nontemporal hints: both streams touch-once (1 GB >> 256 MB L3).

typedef float f32x4 __attribute__((ext_vector_type(4)));

__device__ __forceinline__ f32x4 lif_step(f32x4& v, const f32x4 xt) {
  f32x4 s;
  v.x = v.x + (xt.x - v.x) * 0.5f;
  v.y = v.y + (xt.y - v.y) * 0.5f;
  v.z = v.z + (xt.z - v.z) * 0.5f;
  v.w = v.w + (xt.w - v.w) * 0.5f;
  s.x = (v.x - 1.0f >= 0.0f) ? 1.0f : 0.0f;
  s.y = (v.y - 1.0f >= 0.0f) ? 1.0f : 0.0f;
  s.z = (v.z - 1.0f >= 0.0f) ? 1.0f : 0.0f;
  s.w = (v.w - 1.0f >= 0.0f) ? 1.0f : 0.0f;
  v.x *= (1.0f - s.x);
  v.y *= (1.0f - s.y);
  v.z *= (1.0f - s.z);
  v.w *= (1.0f - s.w);
  return s;
}

__global__ __launch_bounds__(256) void lif_fwd_kernel(
    const f32x4* __restrict__ x, f32x4* __restrict__ out,
    int n4, int T) {
  // Each thread owns two float4 columns: i and i+256 (block-strided so each
  // wave-load is 64 lanes x 16 B contiguous).
  const int i = blockIdx.x * 512 + threadIdx.x;

  const f32x4* __restrict__ px = x + i;
  f32x4* __restrict__ po = out + i;

  f32x4 v0 = (f32x4){0.f, 0.f, 0.f, 0.f};
  f32x4 v1 = (f32x4){0.f, 0.f, 0.f, 0.f};

  // prologue: prefetch t=0
  f32x4 a = __builtin_nontemporal_load(px);
  f32x4 b = __builtin_nontemporal_load(px + 256);

  #pragma unroll 4
  for (int t = 0; t < T - 1; ++t) {
    const size_t offn = (size_t)(t + 1) * n4;
    // issue t+1 loads before t's compute/store (register double-buffer)
    f32x4 na = __builtin_nontemporal_load(px + offn);
    f32x4 nb = __builtin_nontemporal_load(px + offn + 256);

    f32x4 s0 = lif_step(v0, a);
    f32x4 s1 = lif_step(v1, b);

    const size_t offo = (size_t)t * n4;
    __builtin_nontemporal_store(s0, po + offo);
    __builtin_nontemporal_store(s1, po + offo + 256);

    a = na;
    b = nb;
  }

  // epilogue: last timestep
  {
    f32x4 s0 = lif_step(v0, a);
    f32x4 s1 = lif_step(v1, b);
    const size_t offo = (size_t)(T - 1) * n4;
    __builtin_nontemporal_store(s0, po + offo);
    __builtin_nontemporal_store(s1, po + offo + 256);
  }
}

extern "C" void kernel_launch(void* const* d_in, const int* in_sizes, int n_in,
                              void* d_out, int out_size, void* d_ws, size_t ws_size,
                              hipStream_t stream) {
  const float* x = (const float*)d_in[0];
  float* out = (float*)d_out;

  const int T = 32;
  const int total = in_sizes[0];   // T * N
  const int N = total / T;         // 4,194,304
  const int n4 = N / 4;            // 1,048,576 float4 columns

  const int block = 256;
  const int grid = n4 / (block * 2);  // 2048 blocks, 2 float4 per thread

  lif_fwd_kernel<<<grid, block, 0, stream>>>(
      (const f32x4*)x, (f32x4*)out, n4, T);
}

// Round 4
// 191.406 us; speedup vs baseline: 1.1420x; 1.0199x over previous
//
#include <hip/hip_runtime.h>

// LIF forward scan: x[T, N] fp32 -> spikes[T, N] fp32, N = B*C*H*W = 4,194,304.
// Per-column recurrence (exact reference arithmetic, absmax 0.0 R1/R3):
//   v = v + (x_t - v) * 0.5   (TAU=2; *0.5 exact -> FMA-contraction-safe)
//   s = (v - 1.0 >= 0) ? 1 : 0
//   v = (1 - s) * v
//
// R4 vs R3 (195.2 us, 5.50 TB/s eff = 87% of 6.29 TB/s copy ceiling):
//  - 2-timestep bursts: issue 4 loads (next burst), compute 4 lif steps,
//    then 4 back-to-back stores. Doubles per-wave read/write run length
//    -> fewer DRAM read<->write turnarounds at the channel level.
//  - spike result overwrites the x register in place (lif_step returns via
//    the same reg) to keep VGPRs <= ~64 -> 8 waves/SIMD retained.
//  - unchanged: 2 float4 columns/thread block-strided (i, i+256), grid =
//    2048 blocks = 8192 waves = one full residency batch, nontemporal.

typedef float f32x4 __attribute__((ext_vector_type(4)));

// v updated in place; returns spike vector.
__device__ __forceinline__ f32x4 lif_step(f32x4& v, const f32x4 xt) {
  f32x4 s;
  v.x = v.x + (xt.x - v.x) * 0.5f;
  v.y = v.y + (xt.y - v.y) * 0.5f;
  v.z = v.z + (xt.z - v.z) * 0.5f;
  v.w = v.w + (xt.w - v.w) * 0.5f;
  s.x = (v.x - 1.0f >= 0.0f) ? 1.0f : 0.0f;
  s.y = (v.y - 1.0f >= 0.0f) ? 1.0f : 0.0f;
  s.z = (v.z - 1.0f >= 0.0f) ? 1.0f : 0.0f;
  s.w = (v.w - 1.0f >= 0.0f) ? 1.0f : 0.0f;
  v.x *= (1.0f - s.x);
  v.y *= (1.0f - s.y);
  v.z *= (1.0f - s.z);
  v.w *= (1.0f - s.w);
  return s;
}

__global__ __launch_bounds__(256) void lif_fwd_kernel(
    const f32x4* __restrict__ x, f32x4* __restrict__ out,
    int n4, int T) {
  const int i = blockIdx.x * 512 + threadIdx.x;

  const f32x4* __restrict__ px = x + i;
  f32x4* __restrict__ po = out + i;

  f32x4 v0 = (f32x4){0.f, 0.f, 0.f, 0.f};
  f32x4 v1 = (f32x4){0.f, 0.f, 0.f, 0.f};

  // prologue: prefetch burst {t=0, t=1}: a* = t, b* = t+1; *0 = col i, *1 = col i+256
  f32x4 a0 = __builtin_nontemporal_load(px);
  f32x4 a1 = __builtin_nontemporal_load(px + 256);
  f32x4 b0 = __builtin_nontemporal_load(px + n4);
  f32x4 b1 = __builtin_nontemporal_load(px + n4 + 256);

  #pragma unroll 3
  for (int t = 0; t < T - 2; t += 2) {
    // issue next burst's 4 loads (in flight across this burst's compute+store)
    const size_t offn = (size_t)(t + 2) * n4;
    f32x4 na0 = __builtin_nontemporal_load(px + offn);
    f32x4 na1 = __builtin_nontemporal_load(px + offn + 256);
    f32x4 nb0 = __builtin_nontemporal_load(px + offn + n4);
    f32x4 nb1 = __builtin_nontemporal_load(px + offn + n4 + 256);

    // compute 4 lif steps (results reuse the a/b registers)
    a0 = lif_step(v0, a0);   // spike(t, col0)
    a1 = lif_step(v1, a1);   // spike(t, col1)
    b0 = lif_step(v0, b0);   // spike(t+1, col0)
    b1 = lif_step(v1, b1);   // spike(t+1, col1)

    // 4 back-to-back stores
    const size_t offo = (size_t)t * n4;
    __builtin_nontemporal_store(a0, po + offo);
    __builtin_nontemporal_store(a1, po + offo + 256);
    __builtin_nontemporal_store(b0, po + offo + n4);
    __builtin_nontemporal_store(b1, po + offo + n4 + 256);

    a0 = na0; a1 = na1; b0 = nb0; b1 = nb1;
  }

  // epilogue: last burst {T-2, T-1}
  {
    a0 = lif_step(v0, a0);
    a1 = lif_step(v1, a1);
    b0 = lif_step(v0, b0);
    b1 = lif_step(v1, b1);
    const size_t offo = (size_t)(T - 2) * n4;
    __builtin_nontemporal_store(a0, po + offo);
    __builtin_nontemporal_store(a1, po + offo + 256);
    __builtin_nontemporal_store(b0, po + offo + n4);
    __builtin_nontemporal_store(b1, po + offo + n4 + 256);
  }
}

extern "C" void kernel_launch(void* const* d_in, const int* in_sizes, int n_in,
                              void* d_out, int out_size, void* d_ws, size_t ws_size,
                              hipStream_t stream) {
  const float* x = (const float*)d_in[0];
  float* out = (float*)d_out;

  const int T = 32;
  const int total = in_sizes[0];   // T * N
  const int N = total / T;         // 4,194,304
  const int n4 = N / 4;            // 1,048,576 float4 columns

  const int block = 256;
  const int grid = n4 / (block * 2);  // 2048 blocks, 2 float4 per thread

  lif_fwd_kernel<<<grid, block, 0, stream>>>(
      (const f32x4*)x, (f32x4*)out, n4, T);
}

// Round 5
// 182.445 us; speedup vs baseline: 1.1981x; 1.0491x over previous
//
#include <hip/hip_runtime.h>

// LIF forward scan: x[T, N] fp32 -> spikes[T, N] fp32, N = B*C*H*W = 4,194,304.
// Per-column recurrence (exact reference arithmetic, absmax 0.0 R1/R3/R4):
//   v = v + (x_t - v) * 0.5   (TAU=2; *0.5 exact -> FMA-contraction-safe)
//   s = (v - 1.0 >= 0) ? 1 : 0
//   v = (1 - s) * v
//
// R5 vs R4 (191.4 us, 5.61 TB/s = 89% of 6.29 TB/s copy ceiling):
//  - 4 float4 columns per thread (i, i+256, i+512, i+768): each wave's
//    per-timestep read run = 4 KB contiguous, write run = 4 KB contiguous.
//  - grid = 1024 blocks = 4096 waves, all resident (4/SIMD needed, 8 fits);
//    VGPR ~60 (v:16 + cur:16 + next:16 + addr) stays in 8-waves/SIMD class.
//  - one-timestep register prefetch -> 8 KB in flight per wave, >> per-SIMD
//    BW x latency (~2.3 KB).
//  - nontemporal on both streams (touch-once, 1 GB >> 256 MB L3).

typedef float f32x4 __attribute__((ext_vector_type(4)));

// v updated in place; returns spike vector.
__device__ __forceinline__ f32x4 lif_step(f32x4& v, const f32x4 xt) {
  f32x4 s;
  v.x = v.x + (xt.x - v.x) * 0.5f;
  v.y = v.y + (xt.y - v.y) * 0.5f;
  v.z = v.z + (xt.z - v.z) * 0.5f;
  v.w = v.w + (xt.w - v.w) * 0.5f;
  s.x = (v.x - 1.0f >= 0.0f) ? 1.0f : 0.0f;
  s.y = (v.y - 1.0f >= 0.0f) ? 1.0f : 0.0f;
  s.z = (v.z - 1.0f >= 0.0f) ? 1.0f : 0.0f;
  s.w = (v.w - 1.0f >= 0.0f) ? 1.0f : 0.0f;
  v.x *= (1.0f - s.x);
  v.y *= (1.0f - s.y);
  v.z *= (1.0f - s.z);
  v.w *= (1.0f - s.w);
  return s;
}

__global__ __launch_bounds__(256) void lif_fwd_kernel(
    const f32x4* __restrict__ x, f32x4* __restrict__ out,
    int n4, int T) {
  // 4 block-strided float4 columns per thread: wave-contiguous 4 KB runs.
  const int i = blockIdx.x * 1024 + threadIdx.x;

  const f32x4* __restrict__ px = x + i;
  f32x4* __restrict__ po = out + i;

  f32x4 v0 = (f32x4){0.f, 0.f, 0.f, 0.f};
  f32x4 v1 = (f32x4){0.f, 0.f, 0.f, 0.f};
  f32x4 v2 = (f32x4){0.f, 0.f, 0.f, 0.f};
  f32x4 v3 = (f32x4){0.f, 0.f, 0.f, 0.f};

  // prologue: prefetch t=0 (4 loads, 4 KB wave run)
  f32x4 a0 = __builtin_nontemporal_load(px);
  f32x4 a1 = __builtin_nontemporal_load(px + 256);
  f32x4 a2 = __builtin_nontemporal_load(px + 512);
  f32x4 a3 = __builtin_nontemporal_load(px + 768);

  #pragma unroll 2
  for (int t = 0; t < T - 1; ++t) {
    // issue t+1's loads before t's compute/store (register double-buffer)
    const size_t offn = (size_t)(t + 1) * n4;
    f32x4 na0 = __builtin_nontemporal_load(px + offn);
    f32x4 na1 = __builtin_nontemporal_load(px + offn + 256);
    f32x4 na2 = __builtin_nontemporal_load(px + offn + 512);
    f32x4 na3 = __builtin_nontemporal_load(px + offn + 768);

    // compute 4 lif steps (results reuse the a registers)
    a0 = lif_step(v0, a0);
    a1 = lif_step(v1, a1);
    a2 = lif_step(v2, a2);
    a3 = lif_step(v3, a3);

    // 4 back-to-back stores (4 KB wave run)
    const size_t offo = (size_t)t * n4;
    __builtin_nontemporal_store(a0, po + offo);
    __builtin_nontemporal_store(a1, po + offo + 256);
    __builtin_nontemporal_store(a2, po + offo + 512);
    __builtin_nontemporal_store(a3, po + offo + 768);

    a0 = na0; a1 = na1; a2 = na2; a3 = na3;
  }

  // epilogue: last timestep
  {
    a0 = lif_step(v0, a0);
    a1 = lif_step(v1, a1);
    a2 = lif_step(v2, a2);
    a3 = lif_step(v3, a3);
    const size_t offo = (size_t)(T - 1) * n4;
    __builtin_nontemporal_store(a0, po + offo);
    __builtin_nontemporal_store(a1, po + offo + 256);
    __builtin_nontemporal_store(a2, po + offo + 512);
    __builtin_nontemporal_store(a3, po + offo + 768);
  }
}

extern "C" void kernel_launch(void* const* d_in, const int* in_sizes, int n_in,
                              void* d_out, int out_size, void* d_ws, size_t ws_size,
                              hipStream_t stream) {
  const float* x = (const float*)d_in[0];
  float* out = (float*)d_out;

  const int T = 32;
  const int total = in_sizes[0];   // T * N
  const int N = total / T;         // 4,194,304
  const int n4 = N / 4;            // 1,048,576 float4 columns

  const int block = 256;
  const int grid = n4 / (block * 4);  // 1024 blocks, 4 float4 per thread

  lif_fwd_kernel<<<grid, block, 0, stream>>>(
      (const f32x4*)x, (f32x4*)out, n4, T);
}